// Round 9
// baseline (593.936 us; speedup 1.0000x reference)
//
#include <hip/hip_runtime.h>

#define NPTS 65536
#define V 4096
#define C 32
#define HH 64
#define WW 64
#define NSPLIT 4
#define MARG 2.0e-3f

typedef short bf8 __attribute__((ext_vector_type(8)));   // 8 bf16 in 4 VGPRs
typedef float f4 __attribute__((ext_vector_type(4)));

__device__ inline unsigned int ford(float d) {
    unsigned int b = __float_as_uint(d);
    return (b & 0x80000000u) ? ~b : (b | 0x80000000u);
}
__device__ inline short bf16rne(float x) {
    unsigned u = __float_as_uint(x);
    unsigned hb = (u + 0x7FFFu + ((u >> 16) & 1u)) & 0xFFFF0000u;
    return (short)(hb >> 16);
}
__device__ inline float bf16rne_f(float x, short* s) {
    unsigned u = __float_as_uint(x);
    unsigned hb = (u + 0x7FFFu + ((u >> 16) & 1u)) & 0xFFFF0000u;
    *s = (short)(hb >> 16);
    return __uint_as_float(hb);
}
// pack: (bits(a) & ~63) | vtb  -- compiler emits v_and_or_b32
__device__ inline float packkey(float a, unsigned vtb) {
    return __uint_as_float((__float_as_uint(a) & 0xFFFFFFC0u) | vtb);
}

// ---- fused prep: blocks 0-63 EH/EL fragments, 64-79 enneg (+cnt), 80-115 wt ----
__global__ void k_prep(const float* __restrict__ emb, const float* __restrict__ cw,
                       float* __restrict__ enneg, float* __restrict__ wt,
                       bf8* __restrict__ EH, bf8* __restrict__ EL,
                       int* __restrict__ cnt) {
    int bid = blockIdx.x, tid = threadIdx.x;
    if (bid < 64) {                       // codebook -> bf16 hi/lo fragments
        int gid = bid * 256 + tid;        // 16384 = 256 vt * 64 lanes
        int vt = gid >> 6, lane = gid & 63;
        int col = lane & 15, k0 = (lane >> 4) * 8;
        const float* e = emb + (vt * 16 + col) * C + k0;
        bf8 h, l;
#pragma unroll
        for (int j = 0; j < 8; ++j) {
            short hs;
            float hf = bf16rne_f(e[j], &hs);
            h[j] = hs;
            l[j] = bf16rne(e[j] - hf);
        }
        EH[gid] = h;
        EL[gid] = l;
    } else if (bid < 80) {                // enneg = -0.5*||e||^2
        if (bid == 64 && tid == 0) cnt[0] = 0;
        int v = (bid - 64) * 256 + tid;
        const float4* e4 = (const float4*)(emb + v * C);
        float s = 0.f;
#pragma unroll
        for (int j = 0; j < 8; ++j) {
            float4 q = e4[j];
            s += q.x*q.x + q.y*q.y + q.z*q.z + q.w*q.w;
        }
        enneg[v] = -0.5f * s;
    } else {                              // conv weights OIHW -> [i][ky][kx][o]
        int t = (bid - 80) * 256 + tid;
        if (t < C * C * 9) {
            int o = t & 31;
            int r = t >> 5;
            int kx = r % 3;
            int ky = (r / 3) % 3;
            int i  = r / 9;
            wt[t] = cw[((o * C + i) * 3 + ky) * 3 + kx];
        }
    }
}

// ---- MFMA coarse argmin: 64 pts/wave (4 tiles), 1024 codes/split, 1024 blocks ----
// double-buffered LDS, register-prefetched staging, 1 barrier/phase
__global__ __launch_bounds__(256, 4) void k_argmfma(const float* __restrict__ f,
        const bf8* __restrict__ EH, const bf8* __restrict__ EL,
        const float* __restrict__ enneg, float* __restrict__ bvv,
        float* __restrict__ b2a, int* __restrict__ iva) {
    __shared__ bf8 sEH[2][512];    // 2 x 8 vt x 64 lanes = 16KB
    __shared__ bf8 sEL[2][512];
    __shared__ float sen[2][128];

    int tid = threadIdx.x;
    int lane = tid & 63;
    int wv = tid >> 6;
    int ci = blockIdx.x >> 8;        // code split 0..3 (1024 codes)
    int pb = blockIdx.x & 255;       // point block (256 points)
    int base = pb * 256 + wv * 64;
    int col = lane & 15, kb = lane >> 4;

    bf8 xh[4], xl[4];
#pragma unroll
    for (int t = 0; t < 4; ++t) {
        int n = base + t * 16 + col;
        int b = n >> 12, pix = n & 4095;
        const float* fp = f + ((size_t)(b * C + kb * 8)) * 4096 + pix;
#pragma unroll
        for (int j = 0; j < 8; ++j) {
            float x = fp[(size_t)j * 4096];
            short hs;
            float hf = bf16rne_f(x, &hs);
            xh[t][j] = hs;
            xl[t][j] = bf16rne(x - hf);
        }
    }

    float best[16], best2[16];
#pragma unroll
    for (int e = 0; e < 16; ++e) { best[e] = -3.4e38f; best2[e] = -3.4e38f; }

    int off = ci * 4096;   // EH/EL fragment offset for this split
    // prologue: stage phase 0
    {
        bf8 p0 = EH[off + tid], p1 = EH[off + tid + 256];
        bf8 p2 = EL[off + tid], p3 = EL[off + tid + 256];
        sEH[0][tid] = p0; sEH[0][tid + 256] = p1;
        sEL[0][tid] = p2; sEL[0][tid + 256] = p3;
        if (tid < 128) sen[0][tid] = enneg[ci * 1024 + tid];
    }
    __syncthreads();

    int cur = 0;
    for (int ph = 0; ph < 8; ++ph) {
        // prefetch next phase into registers (latency hides under MFMAs below)
        bf8 p0, p1, p2, p3; float ps;
        if (ph < 7) {
            int o2 = off + (ph + 1) * 512;
            p0 = EH[o2 + tid]; p1 = EH[o2 + tid + 256];
            p2 = EL[o2 + tid]; p3 = EL[o2 + tid + 256];
            if (tid < 128) ps = enneg[ci * 1024 + (ph + 1) * 128 + tid];
        }
#pragma unroll
        for (int s2 = 0; s2 < 4; ++s2) {
            int s0 = 2 * s2, s1 = s0 + 1;
            bf8 eh0 = sEH[cur][s0 * 64 + lane], el0 = sEL[cur][s0 * 64 + lane];
            bf8 eh1 = sEH[cur][s1 * 64 + lane], el1 = sEL[cur][s1 * 64 + lane];
            float ng0 = sen[cur][s0 * 16 + col], ng1 = sen[cur][s1 * 16 + col];
            unsigned vtb0 = 63u - (unsigned)(ph * 8 + s0);
            unsigned vtb1 = 63u - (unsigned)(ph * 8 + s1);
#pragma unroll
            for (int t = 0; t < 4; ++t) {
                f4 a0 = {ng0, ng0, ng0, ng0};
                a0 = __builtin_amdgcn_mfma_f32_16x16x32_bf16(xh[t], eh0, a0, 0, 0, 0);
                a0 = __builtin_amdgcn_mfma_f32_16x16x32_bf16(xh[t], el0, a0, 0, 0, 0);
                a0 = __builtin_amdgcn_mfma_f32_16x16x32_bf16(xl[t], eh0, a0, 0, 0, 0);
                f4 a1 = {ng1, ng1, ng1, ng1};
                a1 = __builtin_amdgcn_mfma_f32_16x16x32_bf16(xh[t], eh1, a1, 0, 0, 0);
                a1 = __builtin_amdgcn_mfma_f32_16x16x32_bf16(xh[t], el1, a1, 0, 0, 0);
                a1 = __builtin_amdgcn_mfma_f32_16x16x32_bf16(xl[t], eh1, a1, 0, 0, 0);
#pragma unroll
                for (int r = 0; r < 4; ++r) {
                    int e = t * 4 + r;
                    float k0 = packkey(a0[r], vtb0);
                    float k1 = packkey(a1[r], vtb1);
                    float ob = best[e];
                    best2[e] = fmaxf(best2[e], __builtin_amdgcn_fmed3f(ob, k0, k1));
                    best[e]  = fmaxf(fmaxf(ob, k0), k1);   // -> v_max3_f32
                }
            }
        }
        if (ph < 7) {
            int nxt = cur ^ 1;
            sEH[nxt][tid] = p0; sEH[nxt][tid + 256] = p1;
            sEL[nxt][tid] = p2; sEL[nxt][tid + 256] = p3;
            if (tid < 128) sen[nxt][tid] = ps;
            __syncthreads();
            cur = nxt;
        }
    }

    // decode + 16-col merge + per-split write
#pragma unroll
    for (int t = 0; t < 4; ++t) {
#pragma unroll
        for (int r = 0; r < 4; ++r) {
            float bb = best[t*4+r], b2 = best2[t*4+r];
            int vtl = 63 - (int)(__float_as_uint(bb) & 63u);
            int ii = (ci * 64 + vtl) * 16 + col;
#pragma unroll
            for (int m = 1; m < 16; m <<= 1) {
                float ob  = __shfl_xor(bb, m);
                float ob2 = __shfl_xor(b2, m);
                int   oi  = __shfl_xor(ii, m);
                b2 = fmaxf(fmaxf(b2, ob2), fminf(bb, ob));
                bool take = (ob > bb) || (ob == bb && oi < ii);
                ii = take ? oi : ii;
                bb = fmaxf(bb, ob);
            }
            if (col == 0) {
                int p = base + t * 16 + kb * 4 + r;
                int o = ci * NPTS + p;
                bvv[o] = bb; b2a[o] = b2; iva[o] = ii;
            }
        }
    }
}

// ---- merge 4 splits, write idx, flag ambiguous ----
__global__ void k_merge(const float* __restrict__ bvv, const float* __restrict__ b2a,
                        const int* __restrict__ iva, int* __restrict__ idx,
                        int* __restrict__ cnt, int* __restrict__ flags) {
    int n = blockIdx.x * 256 + threadIdx.x;
    float bb = bvv[n], b2 = b2a[n];
    int ii = iva[n];
#pragma unroll
    for (int s = 1; s < NSPLIT; ++s) {
        float ob  = bvv[s * NPTS + n];
        float ob2 = b2a[s * NPTS + n];
        int   oi  = iva[s * NPTS + n];
        b2 = fmaxf(fmaxf(b2, ob2), fminf(bb, ob));
        bool take = (ob > bb) || (ob == bb && oi < ii);
        ii = take ? oi : ii;
        bb = fmaxf(bb, ob);
    }
    idx[n] = ii;
    if (bb - b2 <= MARG) {
        int pos = atomicAdd(cnt, 1);
        flags[pos] = n;
    }
}

// ---- exact fp32 recheck: 4 points/wave (16 lanes each), 256 codes/lane ----
__global__ __launch_bounds__(256) void k_exact(const float* __restrict__ f,
        const float* __restrict__ emb, const float* __restrict__ enneg,
        const int* __restrict__ cnt, const int* __restrict__ flags,
        int* __restrict__ idx) {
    int nc = cnt[0];
    int nw = (nc + 3) >> 2;                  // waves needed (4 pts each)
    int wv = threadIdx.x >> 6, lane = threadIdx.x & 63;
    int g = lane >> 4, cl = lane & 15;       // point-group, code-lane
    for (int w = blockIdx.x * 4 + wv; w < nw; w += gridDim.x * 4) {
        int fi = w * 4 + g;
        bool valid = fi < nc;
        int n = flags[valid ? fi : 0];
        int b = n >> 12, pix = n & 4095;
        float x[C];
#pragma unroll
        for (int c = 0; c < C; ++c) x[c] = f[((size_t)b * C + c) * 4096 + pix];
        unsigned long long bk = ~0ULL;
        for (int v = 0; v < 256; v += 2) {
            float d[2];
#pragma unroll
            for (int u = 0; u < 2; ++u) {
                int code = (v + u) * 16 + cl;
                const float4* e4 = (const float4*)(emb + code * C);
                float d0 = -enneg[code], d1 = 0.f;   // 0.5||e||^2 - x.e
#pragma unroll
                for (int j = 0; j < 4; ++j) {
                    float4 q = e4[j];
                    d0 = fmaf(q.x, -x[4*j+0], d0);
                    d0 = fmaf(q.y, -x[4*j+1], d0);
                    d0 = fmaf(q.z, -x[4*j+2], d0);
                    d0 = fmaf(q.w, -x[4*j+3], d0);
                }
#pragma unroll
                for (int j = 4; j < 8; ++j) {
                    float4 q = e4[j];
                    d1 = fmaf(q.x, -x[4*j+0], d1);
                    d1 = fmaf(q.y, -x[4*j+1], d1);
                    d1 = fmaf(q.z, -x[4*j+2], d1);
                    d1 = fmaf(q.w, -x[4*j+3], d1);
                }
                d[u] = d0 + d1;
            }
#pragma unroll
            for (int u = 0; u < 2; ++u) {
                unsigned long long k = ((unsigned long long)ford(d[u]) << 32)
                                     | (unsigned int)((v + u) * 16 + cl);
                bk = k < bk ? k : bk;
            }
        }
        // reduce over the 16 lanes of this point-group
#pragma unroll
        for (int m = 1; m < 16; m <<= 1) {
            unsigned long long ok = __shfl_xor(bk, m);
            bk = ok < bk ? ok : bk;
        }
        if (valid && cl == 0) idx[n] = (int)(bk & 0xFFFFu);
    }
}

// ---- fused gather + conv3x3 + Phi + output + loss partials (8x8 tiles, 1024 blocks) ----
__global__ __launch_bounds__(256) void k_conv(const float* __restrict__ f,
                                              const float* __restrict__ emb,
                                              const int* __restrict__ idx,
                                              const float* __restrict__ wt,
                                              const float* __restrict__ cb,
                                              float* __restrict__ out,
                                              float* __restrict__ partial) {
    __shared__ float tile[100 * 36];   // [10][10][36] padded, 14.4KB
    __shared__ float red[256];

    int blk = blockIdx.x;
    int b = blk >> 6, t = blk & 63;
    int y0 = (t >> 3) * 8, x0 = (t & 7) * 8;
    int tid = threadIdx.x;

    {   // gather halo: 100 pts, 2 threads each (16 ch)
        int p = tid >> 1, half = tid & 1;
        if (p < 100) {
            int gy = y0 + p / 10 - 1;
            int gx = x0 + p % 10 - 1;
            float4 e0, e1, e2, e3;
            if (gy >= 0 && gy < HH && gx >= 0 && gx < WW) {
                int id = idx[b * 4096 + gy * WW + gx];
                const float4* e4 = (const float4*)(emb + id * C + half * 16);
                e0 = e4[0]; e1 = e4[1]; e2 = e4[2]; e3 = e4[3];
            } else {
                e0 = e1 = e2 = e3 = make_float4(0.f, 0.f, 0.f, 0.f);
            }
            float4* dst = (float4*)(tile + p * 36 + half * 16);
            dst[0] = e0; dst[1] = e1; dst[2] = e2; dst[3] = e3;
        }
    }
    __syncthreads();

    int lane = tid & 63;
    int ow = __builtin_amdgcn_readfirstlane(tid >> 6);
    int px = lane & 7, py = lane >> 3;

    float acc[8];
    const float* cbp = cb + ow * 8;
#pragma unroll
    for (int j = 0; j < 8; ++j) acc[j] = cbp[j];

#pragma unroll
    for (int ky = 0; ky < 3; ++ky)
#pragma unroll
    for (int kx = 0; kx < 3; ++kx) {
        const float* trow = tile + ((py + ky) * 10 + px + kx) * 36;
#pragma unroll
        for (int i4 = 0; i4 < 8; ++i4) {
            float vv[4];
            *(float4*)vv = *(const float4*)(trow + i4 * 4);
#pragma unroll
            for (int j2 = 0; j2 < 4; ++j2) {
                int i = i4 * 4 + j2;
                const float* w8 = wt + ((i * 3 + ky) * 3 + kx) * C + ow * 8;
                float vj = vv[j2];
#pragma unroll
                for (int o = 0; o < 8; ++o) acc[o] = fmaf(vj, w8[o], acc[o]);
            }
        }
    }

    int y = y0 + py, x = x0 + px;
    const float* center = tile + ((py + 1) * 10 + (px + 1)) * 36 + ow * 8;
    float ls = 0.f;
#pragma unroll
    for (int o = 0; o < 8; ++o) {
        float fh = 0.5f * center[o] + 0.5f * acc[o];
        int oi = ((b * C + ow * 8 + o) * HH + y) * WW + x;
        out[oi] = fh;
        float e = fh - f[oi];
        ls = fmaf(e, e, ls);
    }

    red[tid] = ls;
    __syncthreads();
    for (int s = 128; s > 0; s >>= 1) {
        if (tid < s) red[tid] += red[tid + s];
        __syncthreads();
    }
    if (tid == 0) partial[blk] = red[0];
}

// ---- final loss reduce (1024 partials) ----
__global__ void k_final(const float* __restrict__ partial, float* __restrict__ out_loss) {
    __shared__ float red[256];
    int tid = threadIdx.x;
    red[tid] = partial[tid] + partial[tid + 256] + partial[tid + 512] + partial[tid + 768];
    __syncthreads();
    for (int s = 128; s > 0; s >>= 1) {
        if (tid < s) red[tid] += red[tid + s];
        __syncthreads();
    }
    if (tid == 0) out_loss[0] = 1.25f * red[0] / 2097152.0f;
}

extern "C" void kernel_launch(void* const* d_in, const int* in_sizes, int n_in,
                              void* d_out, int out_size, void* d_ws, size_t ws_size,
                              hipStream_t stream) {
    const float* f   = (const float*)d_in[0];
    const float* emb = (const float*)d_in[1];
    const float* cw  = (const float*)d_in[2];
    const float* cb  = (const float*)d_in[3];
    float* out = (float*)d_out;

    char* w = (char*)d_ws;
    float* enneg   = (float*)w;                 w += V * 4;
    float* wt      = (float*)w;                 w += C * C * 9 * 4;
    int*   idx     = (int*)w;                   w += NPTS * 4;
    int*   flags   = (int*)w;                   w += NPTS * 4;
    int*   cnt     = (int*)w;                   w += 256;
    float* partial = (float*)w;                 w += 1024 * 4;
    bf8*   EH      = (bf8*)w;                   w += 256 * 64 * 16;
    bf8*   EL      = (bf8*)w;                   w += 256 * 64 * 16;
    float* bvv     = (float*)w;                 w += NSPLIT * NPTS * 4;
    float* b2a     = (float*)w;                 w += NSPLIT * NPTS * 4;
    int*   iva     = (int*)w;                   w += NSPLIT * NPTS * 4;

    k_prep<<<116, 256, 0, stream>>>(emb, cw, enneg, wt, EH, EL, cnt);
    k_argmfma<<<256 * NSPLIT, 256, 0, stream>>>(f, EH, EL, enneg, bvv, b2a, iva);
    k_merge<<<NPTS / 256, 256, 0, stream>>>(bvv, b2a, iva, idx, cnt, flags);
    k_exact<<<1024, 256, 0, stream>>>(f, emb, enneg, cnt, flags, idx);
    k_conv<<<1024, 256, 0, stream>>>(f, emb, idx, wt, cb, out, partial);
    k_final<<<1, 256, 0, stream>>>(partial, out + 2097152);
}

// Round 10
// 170.511 us; speedup vs baseline: 3.4833x; 3.4833x over previous
//
#include <hip/hip_runtime.h>

#define NPTS 65536
#define V 4096
#define C 32
#define HH 64
#define WW 64
#define NSPLIT 4
#define MARG 2.0e-3f

typedef short bf8 __attribute__((ext_vector_type(8)));   // 8 bf16 in 4 VGPRs
typedef float f4 __attribute__((ext_vector_type(4)));

__device__ inline unsigned int ford(float d) {
    unsigned int b = __float_as_uint(d);
    return (b & 0x80000000u) ? ~b : (b | 0x80000000u);
}
__device__ inline short bf16rne(float x) {
    unsigned u = __float_as_uint(x);
    unsigned hb = (u + 0x7FFFu + ((u >> 16) & 1u)) & 0xFFFF0000u;
    return (short)(hb >> 16);
}
__device__ inline float bf16rne_f(float x, short* s) {
    unsigned u = __float_as_uint(x);
    unsigned hb = (u + 0x7FFFu + ((u >> 16) & 1u)) & 0xFFFF0000u;
    *s = (short)(hb >> 16);
    return __uint_as_float(hb);
}
// pack: (bits(a) & ~63) | vtb  -- compiler emits v_and_or_b32
__device__ inline float packkey(float a, unsigned vtb) {
    return __uint_as_float((__float_as_uint(a) & 0xFFFFFFC0u) | vtb);
}

// ---- fused prep: blocks 0-63 EH/EL fragments, 64-79 enneg (+counters), 80-115 wt ----
__global__ void k_prep(const float* __restrict__ emb, const float* __restrict__ cw,
                       float* __restrict__ enneg, float* __restrict__ wt,
                       bf8* __restrict__ EH, bf8* __restrict__ EL,
                       int* __restrict__ cnt) {
    int bid = blockIdx.x, tid = threadIdx.x;
    if (bid < 64) {                       // codebook -> bf16 hi/lo fragments
        int gid = bid * 256 + tid;        // 16384 = 256 vt * 64 lanes
        int vt = gid >> 6, lane = gid & 63;
        int col = lane & 15, k0 = (lane >> 4) * 8;
        const float* e = emb + (vt * 16 + col) * C + k0;
        bf8 h, l;
#pragma unroll
        for (int j = 0; j < 8; ++j) {
            short hs;
            float hf = bf16rne_f(e[j], &hs);
            h[j] = hs;
            l[j] = bf16rne(e[j] - hf);
        }
        EH[gid] = h;
        EL[gid] = l;
    } else if (bid < 80) {                // enneg = -0.5*||e||^2
        if (bid == 64 && tid < 2) cnt[tid] = 0;   // cnt[0]=flags, cnt[1]=conv done
        int v = (bid - 64) * 256 + tid;
        const float4* e4 = (const float4*)(emb + v * C);
        float s = 0.f;
#pragma unroll
        for (int j = 0; j < 8; ++j) {
            float4 q = e4[j];
            s += q.x*q.x + q.y*q.y + q.z*q.z + q.w*q.w;
        }
        enneg[v] = -0.5f * s;
    } else {                              // conv weights OIHW -> [i][ky][kx][o]
        int t = (bid - 80) * 256 + tid;
        if (t < C * C * 9) {
            int o = t & 31;
            int r = t >> 5;
            int kx = r % 3;
            int ky = (r / 3) % 3;
            int i  = r / 9;
            wt[t] = cw[((o * C + i) * 3 + ky) * 3 + kx];
        }
    }
}

// ---- MFMA coarse argmin: 32 pts/wave (2 tiles), 1024 codes/split, 2048 blocks ----
__global__ __launch_bounds__(256, 4) void k_argmfma(const float* __restrict__ f,
        const bf8* __restrict__ EH, const bf8* __restrict__ EL,
        const float* __restrict__ enneg, float* __restrict__ bvv,
        float* __restrict__ b2a, int* __restrict__ iva) {
    __shared__ bf8 sEH[512];    // 8 vt * 64 lanes = 8KB
    __shared__ bf8 sEL[512];
    __shared__ float sen[128];

    int tid = threadIdx.x;
    int lane = tid & 63;
    int wv = tid >> 6;
    int ci = blockIdx.x >> 9;        // code split 0..3 (1024 codes)
    int pb = blockIdx.x & 511;       // point block (128 points)
    int base = pb * 128 + wv * 32;
    int col = lane & 15, kb = lane >> 4;

    bf8 xh[2], xl[2];
#pragma unroll
    for (int t = 0; t < 2; ++t) {
        int n = base + t * 16 + col;
        int b = n >> 12, pix = n & 4095;
        const float* fp = f + ((size_t)(b * C + kb * 8)) * 4096 + pix;
#pragma unroll
        for (int j = 0; j < 8; ++j) {
            float x = fp[(size_t)j * 4096];
            short hs;
            float hf = bf16rne_f(x, &hs);
            xh[t][j] = hs;
            xl[t][j] = bf16rne(x - hf);
        }
    }

    float best[8], best2[8];
#pragma unroll
    for (int e = 0; e < 8; ++e) { best[e] = -3.4e38f; best2[e] = -3.4e38f; }

    for (int ph = 0; ph < 8; ++ph) {
        if (ph) __syncthreads();
        int vt0 = ci * 64 + ph * 8;
        int off = vt0 * 64;
        sEH[tid]       = EH[off + tid];
        sEH[tid + 256] = EH[off + tid + 256];
        sEL[tid]       = EL[off + tid];
        sEL[tid + 256] = EL[off + tid + 256];
        if (tid < 128) sen[tid] = enneg[vt0 * 16 + tid];
        __syncthreads();
#pragma unroll
        for (int s2 = 0; s2 < 4; ++s2) {
            int s0 = 2 * s2, s1 = s0 + 1;
            bf8 eh0 = sEH[s0 * 64 + lane], el0 = sEL[s0 * 64 + lane];
            bf8 eh1 = sEH[s1 * 64 + lane], el1 = sEL[s1 * 64 + lane];
            float ng0 = sen[s0 * 16 + col], ng1 = sen[s1 * 16 + col];
            unsigned vtb0 = 63u - (unsigned)(ph * 8 + s0);
            unsigned vtb1 = 63u - (unsigned)(ph * 8 + s1);
#pragma unroll
            for (int t = 0; t < 2; ++t) {
                f4 a0 = {ng0, ng0, ng0, ng0};
                a0 = __builtin_amdgcn_mfma_f32_16x16x32_bf16(xh[t], eh0, a0, 0, 0, 0);
                a0 = __builtin_amdgcn_mfma_f32_16x16x32_bf16(xh[t], el0, a0, 0, 0, 0);
                a0 = __builtin_amdgcn_mfma_f32_16x16x32_bf16(xl[t], eh0, a0, 0, 0, 0);
                f4 a1 = {ng1, ng1, ng1, ng1};
                a1 = __builtin_amdgcn_mfma_f32_16x16x32_bf16(xh[t], eh1, a1, 0, 0, 0);
                a1 = __builtin_amdgcn_mfma_f32_16x16x32_bf16(xh[t], el1, a1, 0, 0, 0);
                a1 = __builtin_amdgcn_mfma_f32_16x16x32_bf16(xl[t], eh1, a1, 0, 0, 0);
#pragma unroll
                for (int r = 0; r < 4; ++r) {
                    int e = t * 4 + r;
                    // exact top-2 merge of {best,best2} with {k0,k1}:
                    //   best2' = max(best2, med3(best, k0, k1)); best' = max3(best, k0, k1)
                    float k0 = packkey(a0[r], vtb0);
                    float k1 = packkey(a1[r], vtb1);
                    float ob = best[e];
                    best2[e] = fmaxf(best2[e], __builtin_amdgcn_fmed3f(ob, k0, k1));
                    best[e]  = fmaxf(fmaxf(ob, k0), k1);   // -> v_max3_f32
                }
            }
        }
    }

    // decode + 16-col merge + per-split write
#pragma unroll
    for (int t = 0; t < 2; ++t) {
#pragma unroll
        for (int r = 0; r < 4; ++r) {
            float bb = best[t*4+r], b2 = best2[t*4+r];
            int vtl = 63 - (int)(__float_as_uint(bb) & 63u);
            int ii = (ci * 64 + vtl) * 16 + col;
#pragma unroll
            for (int m = 1; m < 16; m <<= 1) {
                float ob  = __shfl_xor(bb, m);
                float ob2 = __shfl_xor(b2, m);
                int   oi  = __shfl_xor(ii, m);
                b2 = fmaxf(fmaxf(b2, ob2), fminf(bb, ob));
                bool take = (ob > bb) || (ob == bb && oi < ii);
                ii = take ? oi : ii;
                bb = fmaxf(bb, ob);
            }
            if (col == 0) {
                int p = base + t * 16 + kb * 4 + r;
                int o = ci * NPTS + p;
                bvv[o] = bb; b2a[o] = b2; iva[o] = ii;
            }
        }
    }
}

// ---- merge 4 splits, write idx, flag ambiguous (fkey init for atomicMin) ----
__global__ void k_merge(const float* __restrict__ bvv, const float* __restrict__ b2a,
                        const int* __restrict__ iva, int* __restrict__ idx,
                        int* __restrict__ cnt, int* __restrict__ flags,
                        unsigned long long* __restrict__ fkey) {
    int n = blockIdx.x * 256 + threadIdx.x;
    float bb = bvv[n], b2 = b2a[n];
    int ii = iva[n];
#pragma unroll
    for (int s = 1; s < NSPLIT; ++s) {
        float ob  = bvv[s * NPTS + n];
        float ob2 = b2a[s * NPTS + n];
        int   oi  = iva[s * NPTS + n];
        b2 = fmaxf(fmaxf(b2, ob2), fminf(bb, ob));
        bool take = (ob > bb) || (ob == bb && oi < ii);
        ii = take ? oi : ii;
        bb = fmaxf(bb, ob);
    }
    idx[n] = ii;
    if (bb - b2 <= MARG) {
        int pos = atomicAdd(cnt, 1);
        flags[pos] = n;
        fkey[pos] = ~0ULL;
    }
}

// ---- exact fp32 recheck: 4 waves/point, 16 codes/lane, wave-reduce + 1 atomic ----
__global__ __launch_bounds__(256) void k_exact(const float* __restrict__ f,
        const float* __restrict__ emb, const float* __restrict__ enneg,
        const int* __restrict__ cnt, const int* __restrict__ flags,
        unsigned long long* __restrict__ fkey) {
    int nw = cnt[0] * 4;
    int wv = threadIdx.x >> 6, lane = threadIdx.x & 63;
    for (int w = blockIdx.x * 4 + wv; w < nw; w += gridDim.x * 4) {
        int fi = w >> 2, part = w & 3;
        int n = flags[fi];
        int b = n >> 12, pix = n & 4095;
        float x[C];
#pragma unroll
        for (int c = 0; c < C; ++c) x[c] = f[((size_t)b * C + c) * 4096 + pix];
        float bd = 3.4e38f;
        int bv = 0;
        int c0 = part * 1024 + lane * 16;
        for (int v2 = 0; v2 < 16; ++v2) {
            int code = c0 + v2;
            const float4* e4 = (const float4*)(emb + code * C);
            float d0 = -enneg[code], d1 = 0.f;   // 0.5||e||^2 - x.e
#pragma unroll
            for (int j = 0; j < 4; ++j) {
                float4 q = e4[j];
                d0 = fmaf(q.x, -x[4*j+0], d0);
                d0 = fmaf(q.y, -x[4*j+1], d0);
                d0 = fmaf(q.z, -x[4*j+2], d0);
                d0 = fmaf(q.w, -x[4*j+3], d0);
            }
#pragma unroll
            for (int j = 4; j < 8; ++j) {
                float4 q = e4[j];
                d1 = fmaf(q.x, -x[4*j+0], d1);
                d1 = fmaf(q.y, -x[4*j+1], d1);
                d1 = fmaf(q.z, -x[4*j+2], d1);
                d1 = fmaf(q.w, -x[4*j+3], d1);
            }
            float d = d0 + d1;
            if (d < bd) { bd = d; bv = code; }
        }
        unsigned long long k = ((unsigned long long)ford(bd) << 32) | (unsigned int)bv;
#pragma unroll
        for (int m = 1; m < 64; m <<= 1) {
            unsigned long long ok = __shfl_xor(k, m);
            k = ok < k ? ok : k;
        }
        if (lane == 0) atomicMin(&fkey[fi], k);
    }
}

__global__ void k_fix(const int* __restrict__ cnt, const int* __restrict__ flags,
                      const unsigned long long* __restrict__ fkey, int* __restrict__ idx) {
    int t = blockIdx.x * 256 + threadIdx.x;
    if (t < cnt[0]) idx[flags[t]] = (int)(fkey[t] & 0xFFFFu);
}

// ---- fused gather + conv3x3 + Phi + output + loss (last block reduces) ----
__global__ __launch_bounds__(256) void k_conv(const float* __restrict__ f,
                                              const float* __restrict__ emb,
                                              const int* __restrict__ idx,
                                              const float* __restrict__ wt,
                                              const float* __restrict__ cb,
                                              float* __restrict__ out,
                                              float* __restrict__ partial,
                                              int* __restrict__ cnt) {
    __shared__ float tile[100 * 36];   // [10][10][36] padded, 14.4KB
    __shared__ float red[256];
    __shared__ int lastFlag;

    int blk = blockIdx.x;
    int b = blk >> 6, t = blk & 63;
    int y0 = (t >> 3) * 8, x0 = (t & 7) * 8;
    int tid = threadIdx.x;

    {   // gather halo: 100 pts, 2 threads each (16 ch)
        int p = tid >> 1, half = tid & 1;
        if (p < 100) {
            int gy = y0 + p / 10 - 1;
            int gx = x0 + p % 10 - 1;
            float4 e0, e1, e2, e3;
            if (gy >= 0 && gy < HH && gx >= 0 && gx < WW) {
                int id = idx[b * 4096 + gy * WW + gx];
                const float4* e4 = (const float4*)(emb + id * C + half * 16);
                e0 = e4[0]; e1 = e4[1]; e2 = e4[2]; e3 = e4[3];
            } else {
                e0 = e1 = e2 = e3 = make_float4(0.f, 0.f, 0.f, 0.f);
            }
            float4* dst = (float4*)(tile + p * 36 + half * 16);
            dst[0] = e0; dst[1] = e1; dst[2] = e2; dst[3] = e3;
        }
    }
    __syncthreads();

    int lane = tid & 63;
    int ow = __builtin_amdgcn_readfirstlane(tid >> 6);
    int px = lane & 7, py = lane >> 3;

    float acc[8];
    const float* cbp = cb + ow * 8;
#pragma unroll
    for (int j = 0; j < 8; ++j) acc[j] = cbp[j];

#pragma unroll
    for (int ky = 0; ky < 3; ++ky)
#pragma unroll
    for (int kx = 0; kx < 3; ++kx) {
        const float* trow = tile + ((py + ky) * 10 + px + kx) * 36;
#pragma unroll
        for (int i4 = 0; i4 < 8; ++i4) {
            float vv[4];
            *(float4*)vv = *(const float4*)(trow + i4 * 4);
#pragma unroll
            for (int j2 = 0; j2 < 4; ++j2) {
                int i = i4 * 4 + j2;
                const float* w8 = wt + ((i * 3 + ky) * 3 + kx) * C + ow * 8;
                float vj = vv[j2];
#pragma unroll
                for (int o = 0; o < 8; ++o) acc[o] = fmaf(vj, w8[o], acc[o]);
            }
        }
    }

    int y = y0 + py, x = x0 + px;
    const float* center = tile + ((py + 1) * 10 + (px + 1)) * 36 + ow * 8;
    float ls = 0.f;
#pragma unroll
    for (int o = 0; o < 8; ++o) {
        float fh = 0.5f * center[o] + 0.5f * acc[o];
        int oi = ((b * C + ow * 8 + o) * HH + y) * WW + x;
        out[oi] = fh;
        float e = fh - f[oi];
        ls = fmaf(e, e, ls);
    }

    red[tid] = ls;
    __syncthreads();
    for (int s = 128; s > 0; s >>= 1) {
        if (tid < s) red[tid] += red[tid + s];
        __syncthreads();
    }
    if (tid == 0) {
        partial[blk] = red[0];
        __threadfence();                       // make partial visible device-wide
        int prev = atomicAdd(&cnt[1], 1);
        lastFlag = (prev == 1023);
    }
    __syncthreads();
    if (lastFlag) {                            // last block reduces all partials
        volatile const float* vp = partial;
        red[tid] = vp[tid] + vp[tid + 256] + vp[tid + 512] + vp[tid + 768];
        __syncthreads();
        for (int s = 128; s > 0; s >>= 1) {
            if (tid < s) red[tid] += red[tid + s];
            __syncthreads();
        }
        if (tid == 0) out[2097152] = 1.25f * red[0] / 2097152.0f;
    }
}

extern "C" void kernel_launch(void* const* d_in, const int* in_sizes, int n_in,
                              void* d_out, int out_size, void* d_ws, size_t ws_size,
                              hipStream_t stream) {
    const float* f   = (const float*)d_in[0];
    const float* emb = (const float*)d_in[1];
    const float* cw  = (const float*)d_in[2];
    const float* cb  = (const float*)d_in[3];
    float* out = (float*)d_out;

    char* w = (char*)d_ws;
    float* enneg   = (float*)w;                 w += V * 4;
    float* wt      = (float*)w;                 w += C * C * 9 * 4;
    int*   idx     = (int*)w;                   w += NPTS * 4;
    int*   flags   = (int*)w;                   w += NPTS * 4;
    unsigned long long* fkey = (unsigned long long*)w; w += NPTS * 8;
    int*   cnt     = (int*)w;                   w += 256;
    float* partial = (float*)w;                 w += 1024 * 4;
    bf8*   EH      = (bf8*)w;                   w += 256 * 64 * 16;
    bf8*   EL      = (bf8*)w;                   w += 256 * 64 * 16;
    float* bvv     = (float*)w;                 w += NSPLIT * NPTS * 4;
    float* b2a     = (float*)w;                 w += NSPLIT * NPTS * 4;
    int*   iva     = (int*)w;                   w += NSPLIT * NPTS * 4;

    k_prep<<<116, 256, 0, stream>>>(emb, cw, enneg, wt, EH, EL, cnt);
    k_argmfma<<<512 * NSPLIT, 256, 0, stream>>>(f, EH, EL, enneg, bvv, b2a, iva);
    k_merge<<<NPTS / 256, 256, 0, stream>>>(bvv, b2a, iva, idx, cnt, flags, fkey);
    k_exact<<<1024, 256, 0, stream>>>(f, emb, enneg, cnt, flags, fkey);
    k_fix<<<NPTS / 256, 256, 0, stream>>>(cnt, flags, fkey, idx);
    k_conv<<<1024, 256, 0, stream>>>(f, emb, idx, wt, cb, out, partial, cnt);
}

// Round 11
// 132.265 us; speedup vs baseline: 4.4905x; 1.2892x over previous
//
#include <hip/hip_runtime.h>

#define NPTS 65536
#define V 4096
#define C 32
#define HH 64
#define WW 64
#define NSPLIT 4
#define MARG 2.0e-3f

typedef short bf8 __attribute__((ext_vector_type(8)));   // 8 bf16 in 4 VGPRs
typedef float f4 __attribute__((ext_vector_type(4)));

__device__ inline unsigned int ford(float d) {
    unsigned int b = __float_as_uint(d);
    return (b & 0x80000000u) ? ~b : (b | 0x80000000u);
}
__device__ inline short bf16rne(float x) {
    unsigned u = __float_as_uint(x);
    unsigned hb = (u + 0x7FFFu + ((u >> 16) & 1u)) & 0xFFFF0000u;
    return (short)(hb >> 16);
}
__device__ inline float bf16rne_f(float x, short* s) {
    unsigned u = __float_as_uint(x);
    unsigned hb = (u + 0x7FFFu + ((u >> 16) & 1u)) & 0xFFFF0000u;
    *s = (short)(hb >> 16);
    return __uint_as_float(hb);
}
// pack: (bits(a) & ~63) | vtb  -- compiler emits v_and_or_b32
__device__ inline float packkey(float a, unsigned vtb) {
    return __uint_as_float((__float_as_uint(a) & 0xFFFFFFC0u) | vtb);
}

// ---- fused prep ----
// blocks 0-63: EH/EL argmin fragments; 64-79: enneg (+counter reset);
// 80-95: EB16 bf16 codebook; 96: WB conv B-fragments
__global__ void k_prep(const float* __restrict__ emb, const float* __restrict__ cw,
                       float* __restrict__ enneg, unsigned short* __restrict__ EB16,
                       bf8* __restrict__ EH, bf8* __restrict__ EL,
                       bf8* __restrict__ WB, int* __restrict__ cnt) {
    int bid = blockIdx.x, tid = threadIdx.x;
    if (bid < 64) {                       // codebook -> bf16 hi/lo fragments
        int gid = bid * 256 + tid;        // 16384 = 256 vt * 64 lanes
        int vt = gid >> 6, lane = gid & 63;
        int col = lane & 15, k0 = (lane >> 4) * 8;
        const float* e = emb + (vt * 16 + col) * C + k0;
        bf8 h, l;
#pragma unroll
        for (int j = 0; j < 8; ++j) {
            short hs;
            float hf = bf16rne_f(e[j], &hs);
            h[j] = hs;
            l[j] = bf16rne(e[j] - hf);
        }
        EH[gid] = h;
        EL[gid] = l;
    } else if (bid < 80) {                // enneg = -0.5*||e||^2
        if (bid == 64 && tid < 2) cnt[tid] = 0;   // cnt[0]=flags, cnt[1]=conv done
        int v = (bid - 64) * 256 + tid;
        const float4* e4 = (const float4*)(emb + v * C);
        float s = 0.f;
#pragma unroll
        for (int j = 0; j < 8; ++j) {
            float4 q = e4[j];
            s += q.x*q.x + q.y*q.y + q.z*q.z + q.w*q.w;
        }
        enneg[v] = -0.5f * s;
    } else if (bid < 96) {                // EB16: codebook rows in bf16
        int v = (bid - 80) * 256 + tid;
        const float* e = emb + v * C;
        union { unsigned short us[32]; int4 q[4]; } u;
#pragma unroll
        for (int j = 0; j < 32; ++j) u.us[j] = (unsigned short)bf16rne(e[j]);
        int4* dst = (int4*)(EB16 + v * 32);
#pragma unroll
        for (int j = 0; j < 4; ++j) dst[j] = u.q[j];
    } else {                              // WB: conv weights as MFMA B-fragments
        for (int e = tid; e < 9 * 2 * 64; e += 256) {
            int tap = e >> 7, rem = e & 127, half = rem >> 6, lane = rem & 63;
            int oc = half * 16 + (lane & 15), k0 = (lane >> 4) * 8;
            bf8 w;
#pragma unroll
            for (int j = 0; j < 8; ++j)
                w[j] = bf16rne(cw[oc * 288 + (k0 + j) * 9 + tap]);
            WB[e] = w;
        }
    }
}

// ---- MFMA coarse argmin: 32 pts/wave (2 tiles), 1024 codes/split, 2048 blocks ----
__global__ __launch_bounds__(256, 4) void k_argmfma(const float* __restrict__ f,
        const bf8* __restrict__ EH, const bf8* __restrict__ EL,
        const float* __restrict__ enneg, float* __restrict__ bvv,
        float* __restrict__ b2a, int* __restrict__ iva) {
    __shared__ bf8 sEH[512];    // 8 vt * 64 lanes = 8KB
    __shared__ bf8 sEL[512];
    __shared__ float sen[128];

    int tid = threadIdx.x;
    int lane = tid & 63;
    int wv = tid >> 6;
    int ci = blockIdx.x >> 9;        // code split 0..3 (1024 codes)
    int pb = blockIdx.x & 511;       // point block (128 points)
    int base = pb * 128 + wv * 32;
    int col = lane & 15, kb = lane >> 4;

    bf8 xh[2], xl[2];
#pragma unroll
    for (int t = 0; t < 2; ++t) {
        int n = base + t * 16 + col;
        int b = n >> 12, pix = n & 4095;
        const float* fp = f + ((size_t)(b * C + kb * 8)) * 4096 + pix;
#pragma unroll
        for (int j = 0; j < 8; ++j) {
            float x = fp[(size_t)j * 4096];
            short hs;
            float hf = bf16rne_f(x, &hs);
            xh[t][j] = hs;
            xl[t][j] = bf16rne(x - hf);
        }
    }

    float best[8], best2[8];
#pragma unroll
    for (int e = 0; e < 8; ++e) { best[e] = -3.4e38f; best2[e] = -3.4e38f; }

    for (int ph = 0; ph < 8; ++ph) {
        if (ph) __syncthreads();
        int vt0 = ci * 64 + ph * 8;
        int off = vt0 * 64;
        sEH[tid]       = EH[off + tid];
        sEH[tid + 256] = EH[off + tid + 256];
        sEL[tid]       = EL[off + tid];
        sEL[tid + 256] = EL[off + tid + 256];
        if (tid < 128) sen[tid] = enneg[vt0 * 16 + tid];
        __syncthreads();
#pragma unroll
        for (int s2 = 0; s2 < 4; ++s2) {
            int s0 = 2 * s2, s1 = s0 + 1;
            bf8 eh0 = sEH[s0 * 64 + lane], el0 = sEL[s0 * 64 + lane];
            bf8 eh1 = sEH[s1 * 64 + lane], el1 = sEL[s1 * 64 + lane];
            float ng0 = sen[s0 * 16 + col], ng1 = sen[s1 * 16 + col];
            unsigned vtb0 = 63u - (unsigned)(ph * 8 + s0);
            unsigned vtb1 = 63u - (unsigned)(ph * 8 + s1);
#pragma unroll
            for (int t = 0; t < 2; ++t) {
                f4 a0 = {ng0, ng0, ng0, ng0};
                a0 = __builtin_amdgcn_mfma_f32_16x16x32_bf16(xh[t], eh0, a0, 0, 0, 0);
                a0 = __builtin_amdgcn_mfma_f32_16x16x32_bf16(xh[t], el0, a0, 0, 0, 0);
                a0 = __builtin_amdgcn_mfma_f32_16x16x32_bf16(xl[t], eh0, a0, 0, 0, 0);
                f4 a1 = {ng1, ng1, ng1, ng1};
                a1 = __builtin_amdgcn_mfma_f32_16x16x32_bf16(xh[t], eh1, a1, 0, 0, 0);
                a1 = __builtin_amdgcn_mfma_f32_16x16x32_bf16(xh[t], el1, a1, 0, 0, 0);
                a1 = __builtin_amdgcn_mfma_f32_16x16x32_bf16(xl[t], eh1, a1, 0, 0, 0);
#pragma unroll
                for (int r = 0; r < 4; ++r) {
                    int e = t * 4 + r;
                    float k0 = packkey(a0[r], vtb0);
                    float k1 = packkey(a1[r], vtb1);
                    float ob = best[e];
                    best2[e] = fmaxf(best2[e], __builtin_amdgcn_fmed3f(ob, k0, k1));
                    best[e]  = fmaxf(fmaxf(ob, k0), k1);   // -> v_max3_f32
                }
            }
        }
    }

    // decode + 16-col merge + per-split write
#pragma unroll
    for (int t = 0; t < 2; ++t) {
#pragma unroll
        for (int r = 0; r < 4; ++r) {
            float bb = best[t*4+r], b2 = best2[t*4+r];
            int vtl = 63 - (int)(__float_as_uint(bb) & 63u);
            int ii = (ci * 64 + vtl) * 16 + col;
#pragma unroll
            for (int m = 1; m < 16; m <<= 1) {
                float ob  = __shfl_xor(bb, m);
                float ob2 = __shfl_xor(b2, m);
                int   oi  = __shfl_xor(ii, m);
                b2 = fmaxf(fmaxf(b2, ob2), fminf(bb, ob));
                bool take = (ob > bb) || (ob == bb && oi < ii);
                ii = take ? oi : ii;
                bb = fmaxf(bb, ob);
            }
            if (col == 0) {
                int p = base + t * 16 + kb * 4 + r;
                int o = ci * NPTS + p;
                bvv[o] = bb; b2a[o] = b2; iva[o] = ii;
            }
        }
    }
}

// ---- merge 4 splits, write idx, flag ambiguous (fkey init for atomicMin) ----
__global__ void k_merge(const float* __restrict__ bvv, const float* __restrict__ b2a,
                        const int* __restrict__ iva, int* __restrict__ idx,
                        int* __restrict__ cnt, int* __restrict__ flags,
                        unsigned long long* __restrict__ fkey) {
    int n = blockIdx.x * 256 + threadIdx.x;
    float bb = bvv[n], b2 = b2a[n];
    int ii = iva[n];
#pragma unroll
    for (int s = 1; s < NSPLIT; ++s) {
        float ob  = bvv[s * NPTS + n];
        float ob2 = b2a[s * NPTS + n];
        int   oi  = iva[s * NPTS + n];
        b2 = fmaxf(fmaxf(b2, ob2), fminf(bb, ob));
        bool take = (ob > bb) || (ob == bb && oi < ii);
        ii = take ? oi : ii;
        bb = fmaxf(bb, ob);
    }
    idx[n] = ii;
    if (bb - b2 <= MARG) {
        int pos = atomicAdd(cnt, 1);
        flags[pos] = n;
        fkey[pos] = ~0ULL;
    }
}

// ---- exact fp32 recheck: 4 waves/point, 16 codes/lane, wave-reduce + 1 atomic ----
__global__ __launch_bounds__(256) void k_exact(const float* __restrict__ f,
        const float* __restrict__ emb, const float* __restrict__ enneg,
        const int* __restrict__ cnt, const int* __restrict__ flags,
        unsigned long long* __restrict__ fkey) {
    int nw = cnt[0] * 4;
    int wv = threadIdx.x >> 6, lane = threadIdx.x & 63;
    for (int w = blockIdx.x * 4 + wv; w < nw; w += gridDim.x * 4) {
        int fi = w >> 2, part = w & 3;
        int n = flags[fi];
        int b = n >> 12, pix = n & 4095;
        float x[C];
#pragma unroll
        for (int c = 0; c < C; ++c) x[c] = f[((size_t)b * C + c) * 4096 + pix];
        float bd = 3.4e38f;
        int bv = 0;
        int c0 = part * 1024 + lane * 16;
        for (int v2 = 0; v2 < 16; ++v2) {
            int code = c0 + v2;
            const float4* e4 = (const float4*)(emb + code * C);
            float d0 = -enneg[code], d1 = 0.f;   // 0.5||e||^2 - x.e
#pragma unroll
            for (int j = 0; j < 4; ++j) {
                float4 q = e4[j];
                d0 = fmaf(q.x, -x[4*j+0], d0);
                d0 = fmaf(q.y, -x[4*j+1], d0);
                d0 = fmaf(q.z, -x[4*j+2], d0);
                d0 = fmaf(q.w, -x[4*j+3], d0);
            }
#pragma unroll
            for (int j = 4; j < 8; ++j) {
                float4 q = e4[j];
                d1 = fmaf(q.x, -x[4*j+0], d1);
                d1 = fmaf(q.y, -x[4*j+1], d1);
                d1 = fmaf(q.z, -x[4*j+2], d1);
                d1 = fmaf(q.w, -x[4*j+3], d1);
            }
            float d = d0 + d1;
            if (d < bd) { bd = d; bv = code; }
        }
        unsigned long long k = ((unsigned long long)ford(bd) << 32) | (unsigned int)bv;
#pragma unroll
        for (int m = 1; m < 64; m <<= 1) {
            unsigned long long ok = __shfl_xor(k, m);
            k = ok < k ? ok : k;
        }
        if (lane == 0) atomicMin(&fkey[fi], k);
    }
}

__global__ void k_fix(const int* __restrict__ cnt, const int* __restrict__ flags,
                      const unsigned long long* __restrict__ fkey, int* __restrict__ idx) {
    int t = blockIdx.x * 256 + threadIdx.x;
    if (t < cnt[0]) idx[flags[t]] = (int)(fkey[t] & 0xFFFFu);
}

// ---- MFMA conv: block = 4 rows x 16 px of one image; wave = 1 row ----
__global__ __launch_bounds__(256) void k_conv(const float* __restrict__ f,
        const float* __restrict__ emb, const unsigned short* __restrict__ EB16,
        const bf8* __restrict__ WB, const int* __restrict__ idx,
        const float* __restrict__ cb, float* __restrict__ out,
        float* __restrict__ partial, int* __restrict__ cnt) {
    __shared__ unsigned short ht[108 * 40];   // bf16 h halo tile [6][18][40] 8.6KB
    __shared__ int sid[108];
    __shared__ float S[64 * 34];              // f_hat stage [pix][oc] 8.7KB
    __shared__ float red[256];
    __shared__ int lastFlag;

    int blk = blockIdx.x;
    int b = blk >> 6, t = blk & 63;
    int y0 = (t >> 2) * 4, x0 = (t & 3) * 16;
    int tid = threadIdx.x;

    {   // gather 108 halo points, 2 threads/point (32B each)
        int p = tid >> 1, half = tid & 1;
        if (p < 108) {
            int gy = y0 + p / 18 - 1;
            int gx = x0 + p % 18 - 1;
            int4 v0 = {0,0,0,0}, v1 = {0,0,0,0};
            int id = 0;
            if (gy >= 0 && gy < HH && gx >= 0 && gx < WW) {
                id = idx[b * 4096 + gy * WW + gx];
                const int4* e = (const int4*)(EB16 + id * 32 + half * 16);
                v0 = e[0]; v1 = e[1];
            }
            if (half == 0) sid[p] = id;
            int4* dst = (int4*)(ht + p * 40 + half * 16);
            dst[0] = v0; dst[1] = v1;
        }
    }
    __syncthreads();

    int lane = tid & 63;
    int wv = tid >> 6;            // row within block
    int col = lane & 15;          // pixel-x (A) / oc (B,D)
    int kg = lane >> 4;

    f4 acc0 = {0.f, 0.f, 0.f, 0.f}, acc1 = {0.f, 0.f, 0.f, 0.f};
#pragma unroll
    for (int ky = 0; ky < 3; ++ky)
#pragma unroll
    for (int kx = 0; kx < 3; ++kx) {
        bf8 a = *(const bf8*)(ht + ((wv + ky) * 18 + (col + kx)) * 40 + kg * 8);
        int tap = ky * 3 + kx;
        bf8 w0 = WB[(tap * 2 + 0) * 64 + lane];
        bf8 w1 = WB[(tap * 2 + 1) * 64 + lane];
        acc0 = __builtin_amdgcn_mfma_f32_16x16x32_bf16(a, w0, acc0, 0, 0, 0);
        acc1 = __builtin_amdgcn_mfma_f32_16x16x32_bf16(a, w1, acc1, 0, 0, 0);
    }

    // epilogue: f_hat = 0.5*h_exact + 0.5*(conv + bias), staged for coalesced IO
    float bias0 = cb[col], bias1 = cb[col + 16];
#pragma unroll
    for (int r = 0; r < 4; ++r) {
        int px = kg * 4 + r;
        int id = sid[(wv + 1) * 18 + (px + 1)];
        float h0 = emb[id * 32 + col];
        float h1 = emb[id * 32 + col + 16];
        S[(wv * 16 + px) * 34 + col]      = 0.5f * h0 + 0.5f * (acc0[r] + bias0);
        S[(wv * 16 + px) * 34 + col + 16] = 0.5f * h1 + 0.5f * (acc1[r] + bias1);
    }
    __syncthreads();

    // coalesced store + loss: thread -> oc=t>>3, y=(t&7)>>1, x8=(t&1)*8
    int oc = tid >> 3, yy = (tid & 7) >> 1, x8 = (tid & 1) * 8;
    size_t rb = ((size_t)(b * C + oc) * HH + y0 + yy) * WW + x0 + x8;
    const float* fr = f + rb;
    float* orow = out + rb;
    float ls = 0.f;
#pragma unroll
    for (int i = 0; i < 8; ++i) {
        float fh = S[(yy * 16 + x8 + i) * 34 + oc];
        orow[i] = fh;
        float e = fh - fr[i];
        ls = fmaf(e, e, ls);
    }

    red[tid] = ls;
    __syncthreads();
    for (int s = 128; s > 0; s >>= 1) {
        if (tid < s) red[tid] += red[tid + s];
        __syncthreads();
    }
    if (tid == 0) {
        partial[blk] = red[0];
        __threadfence();
        int prev = atomicAdd(&cnt[1], 1);
        lastFlag = (prev == 1023);
    }
    __syncthreads();
    if (lastFlag) {
        volatile const float* vp = partial;
        red[tid] = vp[tid] + vp[tid + 256] + vp[tid + 512] + vp[tid + 768];
        __syncthreads();
        for (int s = 128; s > 0; s >>= 1) {
            if (tid < s) red[tid] += red[tid + s];
            __syncthreads();
        }
        if (tid == 0) out[2097152] = 1.25f * red[0] / 2097152.0f;
    }
}

extern "C" void kernel_launch(void* const* d_in, const int* in_sizes, int n_in,
                              void* d_out, int out_size, void* d_ws, size_t ws_size,
                              hipStream_t stream) {
    const float* f   = (const float*)d_in[0];
    const float* emb = (const float*)d_in[1];
    const float* cw  = (const float*)d_in[2];
    const float* cb  = (const float*)d_in[3];
    float* out = (float*)d_out;

    char* w = (char*)d_ws;
    float* enneg   = (float*)w;                 w += V * 4;
    int*   idx     = (int*)w;                   w += NPTS * 4;
    int*   flags   = (int*)w;                   w += NPTS * 4;
    unsigned long long* fkey = (unsigned long long*)w; w += NPTS * 8;
    int*   cnt     = (int*)w;                   w += 256;
    float* partial = (float*)w;                 w += 1024 * 4;
    bf8*   EH      = (bf8*)w;                   w += 256 * 64 * 16;
    bf8*   EL      = (bf8*)w;                   w += 256 * 64 * 16;
    unsigned short* EB16 = (unsigned short*)w;  w += V * 32 * 2;
    bf8*   WB      = (bf8*)w;                   w += 9 * 2 * 64 * 16;
    float* bvv     = (float*)w;                 w += NSPLIT * NPTS * 4;
    float* b2a     = (float*)w;                 w += NSPLIT * NPTS * 4;
    int*   iva     = (int*)w;                   w += NSPLIT * NPTS * 4;

    k_prep<<<97, 256, 0, stream>>>(emb, cw, enneg, EB16, EH, EL, WB, cnt);
    k_argmfma<<<512 * NSPLIT, 256, 0, stream>>>(f, EH, EL, enneg, bvv, b2a, iva);
    k_merge<<<NPTS / 256, 256, 0, stream>>>(bvv, b2a, iva, idx, cnt, flags, fkey);
    k_exact<<<1024, 256, 0, stream>>>(f, emb, enneg, cnt, flags, fkey);
    k_fix<<<NPTS / 256, 256, 0, stream>>>(cnt, flags, fkey, idx);
    k_conv<<<1024, 256, 0, stream>>>(f, emb, EB16, WB, idx, cb, out, partial, cnt);
}

// Round 12
// 129.328 us; speedup vs baseline: 4.5925x; 1.0227x over previous
//
#include <hip/hip_runtime.h>

#define NPTS 65536
#define V 4096
#define C 32
#define HH 64
#define WW 64
#define NSPLIT 4
#define MARG 2.0e-3f

typedef short bf8 __attribute__((ext_vector_type(8)));   // 8 bf16 in 4 VGPRs
typedef float f4 __attribute__((ext_vector_type(4)));

__device__ inline unsigned int ford(float d) {
    unsigned int b = __float_as_uint(d);
    return (b & 0x80000000u) ? ~b : (b | 0x80000000u);
}
__device__ inline short bf16rne(float x) {
    unsigned u = __float_as_uint(x);
    unsigned hb = (u + 0x7FFFu + ((u >> 16) & 1u)) & 0xFFFF0000u;
    return (short)(hb >> 16);
}
__device__ inline float bf16rne_f(float x, short* s) {
    unsigned u = __float_as_uint(x);
    unsigned hb = (u + 0x7FFFu + ((u >> 16) & 1u)) & 0xFFFF0000u;
    *s = (short)(hb >> 16);
    return __uint_as_float(hb);
}
// pack: (bits(a) & ~63) | vtb  -- compiler emits v_and_or_b32
__device__ inline float packkey(float a, unsigned vtb) {
    return __uint_as_float((__float_as_uint(a) & 0xFFFFFFC0u) | vtb);
}

// ---- fused prep, flat work items, 402 x 64 threads ----
// [0,16384): EH/EL argmin fragments; [16384,20480): enneg (+counter reset);
// [20480,24576): EB16 bf16 codebook; [24576,25728): WB conv B-fragments
__global__ void k_prep(const float* __restrict__ emb, const float* __restrict__ cw,
                       float* __restrict__ enneg, unsigned short* __restrict__ EB16,
                       bf8* __restrict__ EH, bf8* __restrict__ EL,
                       bf8* __restrict__ WB, int* __restrict__ cnt) {
    int g = blockIdx.x * 64 + threadIdx.x;
    if (g < 16384) {                      // codebook -> bf16 hi/lo fragments
        int vt = g >> 6, lane = g & 63;
        int col = lane & 15, k0 = (lane >> 4) * 8;
        const float* e = emb + (vt * 16 + col) * C + k0;
        bf8 h, l;
#pragma unroll
        for (int j = 0; j < 8; ++j) {
            short hs;
            float hf = bf16rne_f(e[j], &hs);
            h[j] = hs;
            l[j] = bf16rne(e[j] - hf);
        }
        EH[g] = h;
        EL[g] = l;
    } else if (g < 20480) {               // enneg = -0.5*||e||^2
        if (g == 16384) { cnt[0] = 0; cnt[1] = 0; }
        int v = g - 16384;
        const float4* e4 = (const float4*)(emb + v * C);
        float s = 0.f;
#pragma unroll
        for (int j = 0; j < 8; ++j) {
            float4 q = e4[j];
            s += q.x*q.x + q.y*q.y + q.z*q.z + q.w*q.w;
        }
        enneg[v] = -0.5f * s;
    } else if (g < 24576) {               // EB16: codebook rows in bf16
        int v = g - 20480;
        const float* e = emb + v * C;
        union { unsigned short us[32]; int4 q[4]; } u;
#pragma unroll
        for (int j = 0; j < 32; ++j) u.us[j] = (unsigned short)bf16rne(e[j]);
        int4* dst = (int4*)(EB16 + v * 32);
#pragma unroll
        for (int j = 0; j < 4; ++j) dst[j] = u.q[j];
    } else if (g < 25728) {               // WB: conv weights as MFMA B-fragments
        int e = g - 24576;
        int tap = e >> 7, rem = e & 127, half = rem >> 6, lane = rem & 63;
        int oc = half * 16 + (lane & 15), k0 = (lane >> 4) * 8;
        bf8 w;
#pragma unroll
        for (int j = 0; j < 8; ++j)
            w[j] = bf16rne(cw[oc * 288 + (k0 + j) * 9 + tap]);
        WB[e] = w;
    }
}

// ---- MFMA coarse argmin: 32 pts/wave (2 tiles), 1024 codes/split, 2048 blocks ----
__global__ __launch_bounds__(256, 4) void k_argmfma(const float* __restrict__ f,
        const bf8* __restrict__ EH, const bf8* __restrict__ EL,
        const float* __restrict__ enneg, float* __restrict__ bvv,
        float* __restrict__ b2a, int* __restrict__ iva) {
    __shared__ bf8 sEH[512];    // 8 vt * 64 lanes = 8KB
    __shared__ bf8 sEL[512];
    __shared__ float sen[128];

    int tid = threadIdx.x;
    int lane = tid & 63;
    int wv = tid >> 6;
    int ci = blockIdx.x >> 9;        // code split 0..3 (1024 codes)
    int pb = blockIdx.x & 511;       // point block (128 points)
    int base = pb * 128 + wv * 32;
    int col = lane & 15, kb = lane >> 4;

    bf8 xh[2], xl[2];
#pragma unroll
    for (int t = 0; t < 2; ++t) {
        int n = base + t * 16 + col;
        int b = n >> 12, pix = n & 4095;
        const float* fp = f + ((size_t)(b * C + kb * 8)) * 4096 + pix;
#pragma unroll
        for (int j = 0; j < 8; ++j) {
            float x = fp[(size_t)j * 4096];
            short hs;
            float hf = bf16rne_f(x, &hs);
            xh[t][j] = hs;
            xl[t][j] = bf16rne(x - hf);
        }
    }

    float best[8], best2[8];
#pragma unroll
    for (int e = 0; e < 8; ++e) { best[e] = -3.4e38f; best2[e] = -3.4e38f; }

    for (int ph = 0; ph < 8; ++ph) {
        if (ph) __syncthreads();
        int vt0 = ci * 64 + ph * 8;
        int off = vt0 * 64;
        sEH[tid]       = EH[off + tid];
        sEH[tid + 256] = EH[off + tid + 256];
        sEL[tid]       = EL[off + tid];
        sEL[tid + 256] = EL[off + tid + 256];
        if (tid < 128) sen[tid] = enneg[vt0 * 16 + tid];
        __syncthreads();
#pragma unroll
        for (int s2 = 0; s2 < 4; ++s2) {
            int s0 = 2 * s2, s1 = s0 + 1;
            bf8 eh0 = sEH[s0 * 64 + lane], el0 = sEL[s0 * 64 + lane];
            bf8 eh1 = sEH[s1 * 64 + lane], el1 = sEL[s1 * 64 + lane];
            float ng0 = sen[s0 * 16 + col], ng1 = sen[s1 * 16 + col];
            unsigned vtb0 = 63u - (unsigned)(ph * 8 + s0);
            unsigned vtb1 = 63u - (unsigned)(ph * 8 + s1);
#pragma unroll
            for (int t = 0; t < 2; ++t) {
                f4 a0 = {ng0, ng0, ng0, ng0};
                a0 = __builtin_amdgcn_mfma_f32_16x16x32_bf16(xh[t], eh0, a0, 0, 0, 0);
                a0 = __builtin_amdgcn_mfma_f32_16x16x32_bf16(xh[t], el0, a0, 0, 0, 0);
                a0 = __builtin_amdgcn_mfma_f32_16x16x32_bf16(xl[t], eh0, a0, 0, 0, 0);
                f4 a1 = {ng1, ng1, ng1, ng1};
                a1 = __builtin_amdgcn_mfma_f32_16x16x32_bf16(xh[t], eh1, a1, 0, 0, 0);
                a1 = __builtin_amdgcn_mfma_f32_16x16x32_bf16(xh[t], el1, a1, 0, 0, 0);
                a1 = __builtin_amdgcn_mfma_f32_16x16x32_bf16(xl[t], eh1, a1, 0, 0, 0);
#pragma unroll
                for (int r = 0; r < 4; ++r) {
                    int e = t * 4 + r;
                    float k0 = packkey(a0[r], vtb0);
                    float k1 = packkey(a1[r], vtb1);
                    float ob = best[e];
                    best2[e] = fmaxf(best2[e], __builtin_amdgcn_fmed3f(ob, k0, k1));
                    best[e]  = fmaxf(fmaxf(ob, k0), k1);   // -> v_max3_f32
                }
            }
        }
    }

    // decode + 16-col merge + per-split write
#pragma unroll
    for (int t = 0; t < 2; ++t) {
#pragma unroll
        for (int r = 0; r < 4; ++r) {
            float bb = best[t*4+r], b2 = best2[t*4+r];
            int vtl = 63 - (int)(__float_as_uint(bb) & 63u);
            int ii = (ci * 64 + vtl) * 16 + col;
#pragma unroll
            for (int m = 1; m < 16; m <<= 1) {
                float ob  = __shfl_xor(bb, m);
                float ob2 = __shfl_xor(b2, m);
                int   oi  = __shfl_xor(ii, m);
                b2 = fmaxf(fmaxf(b2, ob2), fminf(bb, ob));
                bool take = (ob > bb) || (ob == bb && oi < ii);
                ii = take ? oi : ii;
                bb = fmaxf(bb, ob);
            }
            if (col == 0) {
                int p = base + t * 16 + kb * 4 + r;
                int o = ci * NPTS + p;
                bvv[o] = bb; b2a[o] = b2; iva[o] = ii;
            }
        }
    }
}

// ---- merge 4 splits, write idx, flag ambiguous ----
__global__ void k_merge(const float* __restrict__ bvv, const float* __restrict__ b2a,
                        const int* __restrict__ iva, int* __restrict__ idx,
                        int* __restrict__ cnt, int* __restrict__ flags) {
    int n = blockIdx.x * 256 + threadIdx.x;
    float bb = bvv[n], b2 = b2a[n];
    int ii = iva[n];
#pragma unroll
    for (int s = 1; s < NSPLIT; ++s) {
        float ob  = bvv[s * NPTS + n];
        float ob2 = b2a[s * NPTS + n];
        int   oi  = iva[s * NPTS + n];
        b2 = fmaxf(fmaxf(b2, ob2), fminf(bb, ob));
        bool take = (ob > bb) || (ob == bb && oi < ii);
        ii = take ? oi : ii;
        bb = fmaxf(bb, ob);
    }
    idx[n] = ii;
    if (bb - b2 <= MARG) {
        int pos = atomicAdd(cnt, 1);
        flags[pos] = n;
    }
}

// ---- exact fp32 recheck: 1 block/flagged point, 16 codes/thread, direct idx write ----
__global__ __launch_bounds__(256) void k_exact(const float* __restrict__ f,
        const float* __restrict__ emb, const float* __restrict__ enneg,
        const int* __restrict__ cnt, const int* __restrict__ flags,
        int* __restrict__ idx) {
    __shared__ unsigned long long wred[4];
    int nc = cnt[0];
    int tid = threadIdx.x, wv = tid >> 6, lane = tid & 63;
    for (int fi = blockIdx.x; fi < nc; fi += gridDim.x) {
        int n = flags[fi];
        int b = n >> 12, pix = n & 4095;
        float x[C];
#pragma unroll
        for (int c = 0; c < C; ++c) x[c] = f[((size_t)b * C + c) * 4096 + pix];
        unsigned long long bk = ~0ULL;
        for (int v2 = 0; v2 < 16; v2 += 2) {
            float d[2];
#pragma unroll
            for (int u = 0; u < 2; ++u) {
                int code = (v2 + u) * 256 + tid;
                const float4* e4 = (const float4*)(emb + code * C);
                float d0 = -enneg[code], d1 = 0.f;   // 0.5||e||^2 - x.e
#pragma unroll
                for (int j = 0; j < 4; ++j) {
                    float4 q = e4[j];
                    d0 = fmaf(q.x, -x[4*j+0], d0);
                    d0 = fmaf(q.y, -x[4*j+1], d0);
                    d0 = fmaf(q.z, -x[4*j+2], d0);
                    d0 = fmaf(q.w, -x[4*j+3], d0);
                }
#pragma unroll
                for (int j = 4; j < 8; ++j) {
                    float4 q = e4[j];
                    d1 = fmaf(q.x, -x[4*j+0], d1);
                    d1 = fmaf(q.y, -x[4*j+1], d1);
                    d1 = fmaf(q.z, -x[4*j+2], d1);
                    d1 = fmaf(q.w, -x[4*j+3], d1);
                }
                d[u] = d0 + d1;
            }
#pragma unroll
            for (int u = 0; u < 2; ++u) {
                unsigned long long k = ((unsigned long long)ford(d[u]) << 32)
                                     | (unsigned int)((v2 + u) * 256 + tid);
                bk = k < bk ? k : bk;
            }
        }
#pragma unroll
        for (int m = 1; m < 64; m <<= 1) {
            unsigned long long ok = __shfl_xor(bk, m);
            bk = ok < bk ? ok : bk;
        }
        if (lane == 0) wred[wv] = bk;
        __syncthreads();
        if (tid == 0) {
            unsigned long long k0 = wred[0];
            k0 = wred[1] < k0 ? wred[1] : k0;
            k0 = wred[2] < k0 ? wred[2] : k0;
            k0 = wred[3] < k0 ? wred[3] : k0;
            idx[n] = (int)(k0 & 0xFFFFu);
        }
        __syncthreads();
    }
}

// ---- MFMA conv: block = 4 rows x 16 px of one image; wave = 1 row ----
__global__ __launch_bounds__(256) void k_conv(const float* __restrict__ f,
        const float* __restrict__ emb, const unsigned short* __restrict__ EB16,
        const bf8* __restrict__ WB, const int* __restrict__ idx,
        const float* __restrict__ cb, float* __restrict__ out,
        float* __restrict__ partial, int* __restrict__ cnt) {
    __shared__ unsigned short ht[108 * 40];   // bf16 h halo tile [6][18][40] 8.6KB
    __shared__ int sid[108];
    __shared__ float S[64 * 34];              // f_hat stage [pix][oc] 8.7KB
    __shared__ float red[256];
    __shared__ int lastFlag;

    int blk = blockIdx.x;
    int b = blk >> 6, t = blk & 63;
    int y0 = (t >> 2) * 4, x0 = (t & 3) * 16;
    int tid = threadIdx.x;

    {   // gather 108 halo points, 2 threads/point (32B each)
        int p = tid >> 1, half = tid & 1;
        if (p < 108) {
            int gy = y0 + p / 18 - 1;
            int gx = x0 + p % 18 - 1;
            int4 v0 = {0,0,0,0}, v1 = {0,0,0,0};
            int id = 0;
            if (gy >= 0 && gy < HH && gx >= 0 && gx < WW) {
                id = idx[b * 4096 + gy * WW + gx];
                const int4* e = (const int4*)(EB16 + id * 32 + half * 16);
                v0 = e[0]; v1 = e[1];
            }
            if (half == 0) sid[p] = id;
            int4* dst = (int4*)(ht + p * 40 + half * 16);
            dst[0] = v0; dst[1] = v1;
        }
    }
    __syncthreads();

    int lane = tid & 63;
    int wv = tid >> 6;            // row within block
    int col = lane & 15;          // pixel-x (A) / oc (B,D)
    int kg = lane >> 4;

    f4 acc0 = {0.f, 0.f, 0.f, 0.f}, acc1 = {0.f, 0.f, 0.f, 0.f};
#pragma unroll
    for (int ky = 0; ky < 3; ++ky)
#pragma unroll
    for (int kx = 0; kx < 3; ++kx) {
        bf8 a = *(const bf8*)(ht + ((wv + ky) * 18 + (col + kx)) * 40 + kg * 8);
        int tap = ky * 3 + kx;
        bf8 w0 = WB[(tap * 2 + 0) * 64 + lane];
        bf8 w1 = WB[(tap * 2 + 1) * 64 + lane];
        acc0 = __builtin_amdgcn_mfma_f32_16x16x32_bf16(a, w0, acc0, 0, 0, 0);
        acc1 = __builtin_amdgcn_mfma_f32_16x16x32_bf16(a, w1, acc1, 0, 0, 0);
    }

    // epilogue: f_hat = 0.5*h_exact + 0.5*(conv + bias), staged for coalesced IO
    float bias0 = cb[col], bias1 = cb[col + 16];
#pragma unroll
    for (int r = 0; r < 4; ++r) {
        int px = kg * 4 + r;
        int id = sid[(wv + 1) * 18 + (px + 1)];
        float h0 = emb[id * 32 + col];
        float h1 = emb[id * 32 + col + 16];
        S[(wv * 16 + px) * 34 + col]      = 0.5f * h0 + 0.5f * (acc0[r] + bias0);
        S[(wv * 16 + px) * 34 + col + 16] = 0.5f * h1 + 0.5f * (acc1[r] + bias1);
    }
    __syncthreads();

    // coalesced store + loss: thread -> oc=t>>3, y=(t&7)>>1, x8=(t&1)*8
    int oc = tid >> 3, yy = (tid & 7) >> 1, x8 = (tid & 1) * 8;
    size_t rb = ((size_t)(b * C + oc) * HH + y0 + yy) * WW + x0 + x8;
    const float* fr = f + rb;
    float* orow = out + rb;
    float ls = 0.f;
#pragma unroll
    for (int i = 0; i < 8; ++i) {
        float fh = S[(yy * 16 + x8 + i) * 34 + oc];
        orow[i] = fh;
        float e = fh - fr[i];
        ls = fmaf(e, e, ls);
    }

    red[tid] = ls;
    __syncthreads();
    for (int s = 128; s > 0; s >>= 1) {
        if (tid < s) red[tid] += red[tid + s];
        __syncthreads();
    }
    if (tid == 0) {
        partial[blk] = red[0];
        __threadfence();
        int prev = atomicAdd(&cnt[1], 1);
        lastFlag = (prev == 1023);
    }
    __syncthreads();
    if (lastFlag) {
        volatile const float* vp = partial;
        red[tid] = vp[tid] + vp[tid + 256] + vp[tid + 512] + vp[tid + 768];
        __syncthreads();
        for (int s = 128; s > 0; s >>= 1) {
            if (tid < s) red[tid] += red[tid + s];
            __syncthreads();
        }
        if (tid == 0) out[2097152] = 1.25f * red[0] / 2097152.0f;
    }
}

extern "C" void kernel_launch(void* const* d_in, const int* in_sizes, int n_in,
                              void* d_out, int out_size, void* d_ws, size_t ws_size,
                              hipStream_t stream) {
    const float* f   = (const float*)d_in[0];
    const float* emb = (const float*)d_in[1];
    const float* cw  = (const float*)d_in[2];
    const float* cb  = (const float*)d_in[3];
    float* out = (float*)d_out;

    char* w = (char*)d_ws;
    float* enneg   = (float*)w;                 w += V * 4;
    int*   idx     = (int*)w;                   w += NPTS * 4;
    int*   flags   = (int*)w;                   w += NPTS * 4;
    int*   cnt     = (int*)w;                   w += 256;
    float* partial = (float*)w;                 w += 1024 * 4;
    bf8*   EH      = (bf8*)w;                   w += 256 * 64 * 16;
    bf8*   EL      = (bf8*)w;                   w += 256 * 64 * 16;
    unsigned short* EB16 = (unsigned short*)w;  w += V * 32 * 2;
    bf8*   WB      = (bf8*)w;                   w += 9 * 2 * 64 * 16;
    float* bvv     = (float*)w;                 w += NSPLIT * NPTS * 4;
    float* b2a     = (float*)w;                 w += NSPLIT * NPTS * 4;
    int*   iva     = (int*)w;                   w += NSPLIT * NPTS * 4;

    k_prep<<<402, 64, 0, stream>>>(emb, cw, enneg, EB16, EH, EL, WB, cnt);
    k_argmfma<<<512 * NSPLIT, 256, 0, stream>>>(f, EH, EL, enneg, bvv, b2a, iva);
    k_merge<<<NPTS / 256, 256, 0, stream>>>(bvv, b2a, iva, idx, cnt, flags);
    k_exact<<<1024, 256, 0, stream>>>(f, emb, enneg, cnt, flags, idx);
    k_conv<<<1024, 256, 0, stream>>>(f, emb, EB16, WB, idx, cb, out, partial, cnt);
}